// Round 1
// baseline (2997.299 us; speedup 1.0000x reference)
//
#include <hip/hip_runtime.h>

// Problem shape (fixed by setup_inputs): B=4, N=16384, NPOINT=1024, nsample=1,
// radius=0.5. xyz input layout is [B,3,N] (coords are contiguous per-axis).
// Output: int32 indices [B, NPOINT, 1] = smallest point index within radius of
// each FPS centroid.

constexpr int N_PTS   = 16384;
constexpr int NPOINT  = 1024;
constexpr int BLOCK   = 1024;           // 16 waves
constexpr int KPT     = N_PTS / BLOCK;  // 16 points per thread, held in registers

// ---------------------------------------------------------------------------
// FPS: one block per batch. Points live in registers; block argmax per iter.
// Distance formula replicated exactly as numpy: ((dx*dx + dy*dy) + dz*dz),
// round-to-nearest, no FMA contraction (explicit __f*_rn intrinsics).
// Argmax tie-break: first occurrence (smallest index), matching np.argmax.
// ---------------------------------------------------------------------------
__global__ __launch_bounds__(BLOCK) void fps_kernel(
    const float* __restrict__ xyz,   // [B,3,N]
    int* __restrict__ cent)          // [B,NPOINT] workspace
{
    const int b   = blockIdx.x;
    const int tid = threadIdx.x;
    const float* X = xyz + (size_t)b * 3 * N_PTS;
    const float* Y = X + N_PTS;
    const float* Z = X + 2 * N_PTS;

    float px[KPT], py[KPT], pz[KPT], dst[KPT];
#pragma unroll
    for (int k = 0; k < KPT; ++k) {
        const int p = tid + k * BLOCK;   // strided: coalesced & ascending per thread
        px[k] = X[p];
        py[k] = Y[p];
        pz[k] = Z[p];
        dst[k] = 1e10f;                  // BIG
    }

    __shared__ float s_val[BLOCK / 64];
    __shared__ int   s_idx[BLOCK / 64];
    __shared__ int   s_far;

    const int wave = tid >> 6;
    const int lane = tid & 63;

    // ---- initial far: argmax over x coordinate (first max) ----
    float bv = px[0];
    int   bi = tid;
#pragma unroll
    for (int k = 1; k < KPT; ++k) {
        // ascending index order within thread => '>' keeps first occurrence
        if (px[k] > bv) { bv = px[k]; bi = tid + k * BLOCK; }
    }
    // wave butterfly reduce (max value, tie -> smaller index)
#pragma unroll
    for (int off = 32; off > 0; off >>= 1) {
        float ov = __shfl_xor(bv, off);
        int   oi = __shfl_xor(bi, off);
        if (ov > bv || (ov == bv && oi < bi)) { bv = ov; bi = oi; }
    }
    if (lane == 0) { s_val[wave] = bv; s_idx[wave] = bi; }
    __syncthreads();
    if (tid == 0) {
        float fv = s_val[0];
        int   fi = s_idx[0];
#pragma unroll
        for (int w = 1; w < BLOCK / 64; ++w) {
            const float v = s_val[w];
            const int   i = s_idx[w];
            if (v > fv || (v == fv && i < fi)) { fv = v; fi = i; }
        }
        s_far = fi;
    }
    __syncthreads();
    int far = s_far;

    // ---- main FPS loop ----
    for (int it = 0; it < NPOINT; ++it) {
        if (tid == 0) cent[b * NPOINT + it] = far;   // record PRE-update far
        if (it == NPOINT - 1) break;                 // last update is unused

        // centroid coords (uniform address -> broadcast load, L1/L2 hit)
        const float cx = X[far];
        const float cy = Y[far];
        const float cz = Z[far];

        float nbv = -1.0f;
        int   nbi = N_PTS;
#pragma unroll
        for (int k = 0; k < KPT; ++k) {
            const float dx = __fsub_rn(px[k], cx);
            const float dy = __fsub_rn(py[k], cy);
            const float dz = __fsub_rn(pz[k], cz);
            const float d  = __fadd_rn(
                __fadd_rn(__fmul_rn(dx, dx), __fmul_rn(dy, dy)),
                __fmul_rn(dz, dz));
            const float nd = fminf(dst[k], d);
            dst[k] = nd;
            if (nd > nbv) { nbv = nd; nbi = tid + k * BLOCK; }
        }
#pragma unroll
        for (int off = 32; off > 0; off >>= 1) {
            float ov = __shfl_xor(nbv, off);
            int   oi = __shfl_xor(nbi, off);
            if (ov > nbv || (ov == nbv && oi < nbi)) { nbv = ov; nbi = oi; }
        }
        if (lane == 0) { s_val[wave] = nbv; s_idx[wave] = nbi; }
        __syncthreads();
        if (tid == 0) {
            float fv = s_val[0];
            int   fi = s_idx[0];
#pragma unroll
            for (int w = 1; w < BLOCK / 64; ++w) {
                const float v = s_val[w];
                const int   i = s_idx[w];
                if (v > fv || (v == fv && i < fi)) { fv = v; fi = i; }
            }
            s_far = fi;
        }
        __syncthreads();
        far = s_far;
    }
}

// ---------------------------------------------------------------------------
// Ball query, nsample=1: one wave per centroid; scan 64-point chunks from
// index 0, first hit wins (== min index within radius). Distance replicated
// as the reference's einsum expansion: ((-2*dot) + |c|^2) + |p|^2, and the
// keep-test is !(d > r^2)  i.e. d <= 0.25.
// ---------------------------------------------------------------------------
__global__ __launch_bounds__(256) void ballq_kernel(
    const float* __restrict__ xyz,   // [B,3,N]
    const int* __restrict__ cent,    // [B,NPOINT]
    int* __restrict__ out)           // [B,NPOINT]
{
    const int gw   = (blockIdx.x * 256 + threadIdx.x) >> 6; // global wave id
    const int lane = threadIdx.x & 63;
    const int b = gw / NPOINT;
    const int s = gw % NPOINT;

    const float* X = xyz + (size_t)b * 3 * N_PTS;
    const float* Y = X + N_PTS;
    const float* Z = X + 2 * N_PTS;

    const int ci = cent[b * NPOINT + s];
    const float cx = X[ci];
    const float cy = Y[ci];
    const float cz = Z[ci];
    const float cn = __fadd_rn(
        __fadd_rn(__fmul_rn(cx, cx), __fmul_rn(cy, cy)), __fmul_rn(cz, cz));

    int res = N_PTS;
    for (int base = 0; base < N_PTS; base += 64) {
        const int p = base + lane;
        const float x = X[p];
        const float y = Y[p];
        const float z = Z[p];
        const float dot = __fadd_rn(
            __fadd_rn(__fmul_rn(x, cx), __fmul_rn(y, cy)), __fmul_rn(z, cz));
        const float pn = __fadd_rn(
            __fadd_rn(__fmul_rn(x, x), __fmul_rn(y, y)), __fmul_rn(z, z));
        const float d = __fadd_rn(__fadd_rn(__fmul_rn(-2.0f, dot), cn), pn);
        const bool hit = !(d > 0.25f);
        const unsigned long long m = __ballot(hit);
        if (m) {                       // wave-uniform branch
            res = base + (__ffsll((long long)m) - 1);
            break;
        }
    }
    if (lane == 0) out[b * NPOINT + s] = res;
}

extern "C" void kernel_launch(void* const* d_in, const int* in_sizes, int n_in,
                              void* d_out, int out_size, void* d_ws, size_t ws_size,
                              hipStream_t stream) {
    const float* xyz = (const float*)d_in[0];
    // cls_label (d_in[1]) and npoint scalar (d_in[2]) don't affect the output
    // values; shapes are fixed by the problem (npoint = out_size / B = 1024).
    const int B = in_sizes[1] / 16;          // cls_label is [B,16]
    int* cent = (int*)d_ws;                  // [B, NPOINT] scratch
    int* out  = (int*)d_out;                 // int32 [B, NPOINT, 1]

    fps_kernel<<<B, BLOCK, 0, stream>>>(xyz, cent);

    const int nwaves  = B * NPOINT;          // one wave per centroid
    const int nblocks = nwaves / 4;          // 256 threads = 4 waves/block
    ballq_kernel<<<nblocks, 256, 0, stream>>>(xyz, cent, out);
}

// Round 2
// 1869.225 us; speedup vs baseline: 1.6035x; 1.6035x over previous
//
#include <hip/hip_runtime.h>

// Problem shape (fixed by setup_inputs): B=4, N=16384, NPOINT=1024, nsample=1,
// radius=0.5. xyz input layout is [B,3,N]. Output: int32 [B,NPOINT,1] =
// smallest point index within radius of each FPS centroid.

constexpr int N_PTS  = 16384;
constexpr int NPOINT = 1024;
constexpr int BLOCK  = 512;            // 8 waves -> 2 waves/SIMD
constexpr int KPT    = N_PTS / BLOCK;  // 32 points/thread in registers
constexpr int NWAVE  = BLOCK / 64;     // 8

// Packed argmax key: distances (and x-coords) are >= 0, so IEEE bit pattern
// order == float order. High 32 bits = value bits, low bits = (N-1-idx) so
// u64 max gives (max value, tie -> min index) == np.argmax semantics.
__device__ inline unsigned long long pack_key(float v, int idx) {
    return ((unsigned long long)__float_as_uint(v) << 32) |
           (unsigned)(N_PTS - 1 - idx);
}
__device__ inline int key_idx(unsigned long long k) {
    return N_PTS - 1 - (int)(k & 0xFFFFu);
}

// ---------------------------------------------------------------------------
// FPS: one block per batch. 32 points/thread in VGPRs. Per iteration:
// register scan -> 6-step packed-key wave butterfly -> leader writes LDS
// (double-buffered) -> ONE barrier -> all threads redundantly reduce the 8
// wave keys. Distance replicated exactly as numpy: ((dx*dx+dy*dy)+dz*dz),
// round-to-nearest, no FMA contraction.
// ---------------------------------------------------------------------------
__global__ __launch_bounds__(BLOCK, 2) void fps_kernel(
    const float* __restrict__ xyz,   // [B,3,N]
    int* __restrict__ cent)          // [B,NPOINT] workspace
{
    const int b   = blockIdx.x;
    const int tid = threadIdx.x;
    const float* X = xyz + (size_t)b * 3 * N_PTS;
    const float* Y = X + N_PTS;
    const float* Z = X + 2 * N_PTS;

    float px[KPT], py[KPT], pz[KPT], dst[KPT];
#pragma unroll
    for (int k = 0; k < KPT; ++k) {
        const int p = tid + k * BLOCK;   // strided: coalesced, ascending per thread
        px[k] = X[p];
        py[k] = Y[p];
        pz[k] = Z[p];
        dst[k] = 1e10f;                  // BIG
    }

    __shared__ unsigned long long s_key[2][NWAVE];  // double-buffered

    const int wave = tid >> 6;
    const int lane = tid & 63;

    // ---- initial far: argmax over x (first max) ----
    {
        float bv = px[0];
        int   bi = tid;
#pragma unroll
        for (int k = 1; k < KPT; ++k) {
            // ascending index within thread => '>' keeps first occurrence
            if (px[k] > bv) { bv = px[k]; bi = tid + k * BLOCK; }
        }
        unsigned long long key = pack_key(bv, bi);
#pragma unroll
        for (int off = 32; off > 0; off >>= 1) {
            unsigned long long o = __shfl_xor(key, off);
            if (o > key) key = o;
        }
        if (lane == 0) s_key[0][wave] = key;
    }
    __syncthreads();
    unsigned long long bk = s_key[0][0];
#pragma unroll
    for (int w = 1; w < NWAVE; ++w) {
        const unsigned long long o = s_key[0][w];
        if (o > bk) bk = o;
    }
    int far = __builtin_amdgcn_readfirstlane(key_idx(bk));

    // ---- main FPS loop: one barrier per iteration ----
    for (int it = 0; it < NPOINT; ++it) {
        if (tid == 0) cent[b * NPOINT + it] = far;   // record PRE-update far
        if (it == NPOINT - 1) break;                 // last update is unused

        // centroid coords: far is in an SGPR -> scalar broadcast loads
        const float cx = X[far];
        const float cy = Y[far];
        const float cz = Z[far];

        float nbv = -1.0f;
        int   nbi = N_PTS;
#pragma unroll
        for (int k = 0; k < KPT; ++k) {
            const float dx = __fsub_rn(px[k], cx);
            const float dy = __fsub_rn(py[k], cy);
            const float dz = __fsub_rn(pz[k], cz);
            const float d  = __fadd_rn(
                __fadd_rn(__fmul_rn(dx, dx), __fmul_rn(dy, dy)),
                __fmul_rn(dz, dz));
            const float nd = fminf(dst[k], d);
            dst[k] = nd;
            if (nd > nbv) { nbv = nd; nbi = tid + k * BLOCK; }
        }

        unsigned long long key = pack_key(nbv, nbi);
#pragma unroll
        for (int off = 32; off > 0; off >>= 1) {
            unsigned long long o = __shfl_xor(key, off);
            if (o > key) key = o;
        }
        const int buf = (it + 1) & 1;
        if (lane == 0) s_key[buf][wave] = key;
        __syncthreads();

        unsigned long long k0 = s_key[buf][0];
#pragma unroll
        for (int w = 1; w < NWAVE; ++w) {
            const unsigned long long o = s_key[buf][w];
            if (o > k0) k0 = o;
        }
        far = __builtin_amdgcn_readfirstlane(key_idx(k0));
    }
}

// ---------------------------------------------------------------------------
// Ball query, nsample=1: one wave per centroid; scan 64-point chunks from
// index 0, first hit wins (== min index within radius). Distance replicated
// as the reference einsum: ((-2*dot) + |c|^2) + |p|^2; keep-test d <= 0.25.
// ---------------------------------------------------------------------------
__global__ __launch_bounds__(256) void ballq_kernel(
    const float* __restrict__ xyz,   // [B,3,N]
    const int* __restrict__ cent,    // [B,NPOINT]
    int* __restrict__ out)           // [B,NPOINT]
{
    const int gw   = (blockIdx.x * 256 + threadIdx.x) >> 6; // global wave id
    const int lane = threadIdx.x & 63;
    const int b = gw / NPOINT;
    const int s = gw % NPOINT;

    const float* X = xyz + (size_t)b * 3 * N_PTS;
    const float* Y = X + N_PTS;
    const float* Z = X + 2 * N_PTS;

    const int ci = cent[b * NPOINT + s];
    const float cx = X[ci];
    const float cy = Y[ci];
    const float cz = Z[ci];
    const float cn = __fadd_rn(
        __fadd_rn(__fmul_rn(cx, cx), __fmul_rn(cy, cy)), __fmul_rn(cz, cz));

    int res = N_PTS;
    for (int base = 0; base < N_PTS; base += 64) {
        const int p = base + lane;
        const float x = X[p];
        const float y = Y[p];
        const float z = Z[p];
        const float dot = __fadd_rn(
            __fadd_rn(__fmul_rn(x, cx), __fmul_rn(y, cy)), __fmul_rn(z, cz));
        const float pn = __fadd_rn(
            __fadd_rn(__fmul_rn(x, x), __fmul_rn(y, y)), __fmul_rn(z, z));
        const float d = __fadd_rn(__fadd_rn(__fmul_rn(-2.0f, dot), cn), pn);
        const bool hit = !(d > 0.25f);
        const unsigned long long m = __ballot(hit);
        if (m) {                       // wave-uniform branch
            res = base + (__ffsll((long long)m) - 1);
            break;
        }
    }
    if (lane == 0) out[b * NPOINT + s] = res;
}

extern "C" void kernel_launch(void* const* d_in, const int* in_sizes, int n_in,
                              void* d_out, int out_size, void* d_ws, size_t ws_size,
                              hipStream_t stream) {
    const float* xyz = (const float*)d_in[0];
    const int B = in_sizes[1] / 16;          // cls_label is [B,16]
    int* cent = (int*)d_ws;                  // [B, NPOINT] scratch
    int* out  = (int*)d_out;                 // int32 [B, NPOINT, 1]

    fps_kernel<<<B, BLOCK, 0, stream>>>(xyz, cent);

    const int nwaves  = B * NPOINT;          // one wave per centroid
    const int nblocks = nwaves / 4;          // 256 threads = 4 waves/block
    ballq_kernel<<<nblocks, 256, 0, stream>>>(xyz, cent, out);
}